// Round 1
// baseline (2297.318 us; speedup 1.0000x reference)
//
#include <hip/hip_runtime.h>
#include <math.h>

#define B_     32
#define C_     256
#define H_     56
#define W_     56
#define HW     3136      // 56*56
#define LSTMH  10

// ---------------------------------------------------------------------------
// K1: per-(b,c) spatial mean of x  -> g_mean[8192]
// ---------------------------------------------------------------------------
__global__ __launch_bounds__(256) void k_mean(const float* __restrict__ x,
                                              float* __restrict__ g_mean) {
    const int plane = blockIdx.x;                 // b*C + c
    const float4* xp = (const float4*)(x + (size_t)plane * HW);
    float s = 0.f;
    for (int i = threadIdx.x; i < HW / 4; i += 256) {
        float4 v = xp[i];
        s += (v.x + v.y) + (v.z + v.w);
    }
    #pragma unroll
    for (int off = 32; off > 0; off >>= 1) s += __shfl_down(s, off, 64);
    __shared__ float ls[4];
    if ((threadIdx.x & 63) == 0) ls[threadIdx.x >> 6] = s;
    __syncthreads();
    if (threadIdx.x == 0) {
        float t = (ls[0] + ls[1]) + (ls[2] + ls[3]);
        g_mean[plane] = t / (float)HW;
    }
}

// ---------------------------------------------------------------------------
// K2: layer gate (1x1 conv on means -> LSTM cell -> fc -> round(sigmoid))
// grid = 32 blocks (one per batch), 64 threads
// ---------------------------------------------------------------------------
__global__ __launch_bounds__(64) void k_layer_gate(
        const float* __restrict__ g_mean,
        const float* __restrict__ lgw,   // (10,256)
        const float* __restrict__ lgb,   // (10)
        const float* __restrict__ w_ih,  // (40,10)
        const float* __restrict__ b_ih,  // (40)
        const float* __restrict__ b_hh,  // (40)
        const float* __restrict__ fcw,   // (1,10)
        const float* __restrict__ fcb,   // (1)
        float* __restrict__ layer_out)   // (32)
{
    const int b = blockIdx.x;
    __shared__ float g[C_];
    __shared__ float h[LSTMH];
    for (int i = threadIdx.x; i < C_; i += 64) g[i] = g_mean[b * C_ + i];
    __syncthreads();
    if (threadIdx.x < LSTMH) {
        const int j = threadIdx.x;
        float s = lgb[j];
        for (int c = 0; c < C_; ++c) s = fmaf(g[c], lgw[j * C_ + c], s);
        h[j] = fmaxf(s, 0.f);
    }
    __syncthreads();
    if (threadIdx.x == 0) {
        float gates[40];
        #pragma unroll
        for (int k = 0; k < 40; ++k) {
            float s = b_ih[k] + b_hh[k];
            #pragma unroll
            for (int j = 0; j < LSTMH; ++j) s = fmaf(h[j], w_ih[k * LSTMH + j], s);
            gates[k] = s;
        }
        float outv = fcb[0];
        #pragma unroll
        for (int k = 0; k < LSTMH; ++k) {
            float ig = gates[k];         // i
            float gg = gates[20 + k];    // g  (f = gates[10+k] is dead in ref)
            float og = gates[30 + k];    // o
            float c  = (1.f / (1.f + expf(-ig))) * tanhf(gg);
            float hs = (1.f / (1.f + expf(-og))) * tanhf(c);
            outv = fmaf(hs, fcw[k], outv);
        }
        outv = fmaxf(outv, 0.f);
        layer_out[b] = rintf(1.f / (1.f + expf(-outv)));   // half-even, like jnp.round
    }
}

// ---------------------------------------------------------------------------
// K3: channel-gate conv (3x3, stride2, pad0 -> 27x27) + bias + relu + spatial mean
// grid = (64 co-groups, 32 b), 256 threads; each thread: up to 3 output pixels x 4 co
// ---------------------------------------------------------------------------
__global__ __launch_bounds__(256) void k_cg_conv(
        const float* __restrict__ x,
        const float* __restrict__ w,     // (256,256,3,3)
        const float* __restrict__ bias,  // (256)
        float* __restrict__ cg_s)        // (32,256) mean of relu(conv+b)
{
    __shared__ float plane[HW];
    const int b = blockIdx.y, cog = blockIdx.x, tid = threadIdx.x;
    const int co0 = cog * 4;
    const int i0 = tid, i1 = tid + 256, i2 = tid + 512;
    const int oh0 = i0 / 27, ow0 = i0 - oh0 * 27;
    const int oh1 = i1 / 27, ow1 = i1 - oh1 * 27;
    const int has2 = (i2 < 729);
    const int oh2 = has2 ? (i2 / 27) : 0;
    const int ow2 = has2 ? (i2 - (i2 / 27) * 27) : 0;

    float acc[4][3] = {};
    const float* xb = x + (size_t)b * C_ * HW;

    for (int ci = 0; ci < C_; ++ci) {
        __syncthreads();
        const float4* xp = (const float4*)(xb + (size_t)ci * HW);
        for (int i = tid; i < HW / 4; i += 256) ((float4*)plane)[i] = xp[i];
        __syncthreads();

        float win0[9], win1[9], win2[9];
        #pragma unroll
        for (int dr = 0; dr < 3; ++dr)
            #pragma unroll
            for (int dc = 0; dc < 3; ++dc) {
                win0[dr * 3 + dc] = plane[(2 * oh0 + dr) * W_ + 2 * ow0 + dc];
                win1[dr * 3 + dc] = plane[(2 * oh1 + dr) * W_ + 2 * ow1 + dc];
                win2[dr * 3 + dc] = has2 ? plane[(2 * oh2 + dr) * W_ + 2 * ow2 + dc] : 0.f;
            }
        const float* wrow = w + (size_t)(co0 * C_ + ci) * 9;
        #pragma unroll
        for (int j = 0; j < 4; ++j) {
            const float* wt = wrow + (size_t)j * C_ * 9;
            float w9[9];
            #pragma unroll
            for (int t = 0; t < 9; ++t) w9[t] = wt[t];
            #pragma unroll
            for (int t = 0; t < 9; ++t) {
                acc[j][0] = fmaf(win0[t], w9[t], acc[j][0]);
                acc[j][1] = fmaf(win1[t], w9[t], acc[j][1]);
                acc[j][2] = fmaf(win2[t], w9[t], acc[j][2]);
            }
        }
    }
    __syncthreads();  // done with plane; reuse for reduction
    #pragma unroll
    for (int j = 0; j < 4; ++j) {
        const float bi = bias[co0 + j];
        float s = fmaxf(acc[j][0] + bi, 0.f) + fmaxf(acc[j][1] + bi, 0.f);
        if (has2) s += fmaxf(acc[j][2] + bi, 0.f);
        #pragma unroll
        for (int off = 32; off > 0; off >>= 1) s += __shfl_down(s, off, 64);
        if ((tid & 63) == 0) plane[j * 4 + (tid >> 6)] = s;
    }
    __syncthreads();
    if (tid < 4) {
        const int j = tid;
        float t = (plane[j * 4] + plane[j * 4 + 1]) + (plane[j * 4 + 2] + plane[j * 4 + 3]);
        cg_s[b * C_ + co0 + j] = t / 729.f;
    }
}

// ---------------------------------------------------------------------------
// K4: channel fc -> mask[b][co] = rintf(sigmoid(relu(.))); skip[b]
// grid = 32 blocks, 256 threads (one per co)
// ---------------------------------------------------------------------------
__global__ __launch_bounds__(256) void k_channel_fc(
        const float* __restrict__ cg_s,
        const float* __restrict__ fcw,   // (256,256)
        const float* __restrict__ fcb,   // (256)
        const float* __restrict__ layer, // (32)
        float* __restrict__ mask,        // (32,256)
        float* __restrict__ skipf)       // (32)
{
    const int b = blockIdx.x, co = threadIdx.x;
    __shared__ float g[C_];
    g[co] = cg_s[b * C_ + co];
    __syncthreads();
    float s = fcb[co];
    for (int c = 0; c < C_; ++c) s = fmaf(g[c], fcw[co * C_ + c], s);
    const float f = fmaxf(s, 0.f);
    const float m = rintf(1.f / (1.f + expf(-f)));
    mask[b * C_ + co] = m;
    float cnt = m;
    #pragma unroll
    for (int off = 32; off > 0; off >>= 1) cnt += __shfl_down(cnt, off, 64);
    __shared__ float cs[4];
    if ((co & 63) == 0) cs[co >> 6] = cnt;
    __syncthreads();
    if (co == 0) {
        const float total = (cs[0] + cs[1]) + (cs[2] + cs[3]);
        skipf[b] = (layer[b] < 0.5f || total < 0.5f) ? 1.f : 0.f;
    }
}

// ---------------------------------------------------------------------------
// K5: main conv (3x3, stride1, pad1) + gated blend.
// grid = (64 co-groups, 32 b), 448 threads.
// thread -> (row r = tid>>3, col segment of 7). LDS: 58x58 zero-padded plane.
// Masked-off co planes are a pure x copy (no conv work).
// ---------------------------------------------------------------------------
__device__ __forceinline__ void conv_acc7(float acc[7], const float win[3][9],
                                          const float* __restrict__ wt) {
    float w9[9];
    #pragma unroll
    for (int t = 0; t < 9; ++t) w9[t] = wt[t];
    #pragma unroll
    for (int p = 0; p < 7; ++p) {
        float s = acc[p];
        #pragma unroll
        for (int dr = 0; dr < 3; ++dr)
            #pragma unroll
            for (int dk = 0; dk < 3; ++dk)
                s = fmaf(win[dr][p + dk], w9[dr * 3 + dk], s);
        acc[p] = s;
    }
}

__global__ __launch_bounds__(448) void k_main_conv(
        const float* __restrict__ x,
        const float* __restrict__ w,      // (256,256,3,3)
        const float* __restrict__ mask,   // (32,256)
        const float* __restrict__ skipf,  // (32)
        float* __restrict__ out)
{
    __shared__ float lds[58 * 58];
    const int b = blockIdx.y, cog = blockIdx.x, tid = threadIdx.x;
    const int co0 = cog * 4;
    const float* xb = x + (size_t)b * C_ * HW;
    float* ob = out + (size_t)b * C_ * HW;

    const int sk = (skipf[b] > 0.5f) ? 1 : 0;
    int m0 = (!sk && mask[b * C_ + co0 + 0] > 0.5f) ? 1 : 0;
    int m1 = (!sk && mask[b * C_ + co0 + 1] > 0.5f) ? 1 : 0;
    int m2 = (!sk && mask[b * C_ + co0 + 2] > 0.5f) ? 1 : 0;
    int m3 = (!sk && mask[b * C_ + co0 + 3] > 0.5f) ? 1 : 0;
    // block-uniform by construction; make it scalar for the branches below
    m0 = __builtin_amdgcn_readfirstlane(m0);
    m1 = __builtin_amdgcn_readfirstlane(m1);
    m2 = __builtin_amdgcn_readfirstlane(m2);
    m3 = __builtin_amdgcn_readfirstlane(m3);

    if (!(m0 | m1 | m2 | m3)) {   // whole group is pass-through: copy 4 planes
        const float4* s4 = (const float4*)(xb + (size_t)co0 * HW);
        float4* d4 = (float4*)(ob + (size_t)co0 * HW);
        for (int i = tid; i < 4 * (HW / 4); i += 448) d4[i] = s4[i];
        return;
    }

    for (int i = tid; i < 58 * 58; i += 448) lds[i] = 0.f;   // zero halo once

    const int r = tid >> 3;            // 0..55
    const int c0 = (tid & 7) * 7;      // 0,7,...,49
    float acc0[7] = {}, acc1[7] = {}, acc2[7] = {}, acc3[7] = {};

    for (int ci = 0; ci < C_; ++ci) {
        __syncthreads();
        const float4* xp = (const float4*)(xb + (size_t)ci * HW);
        for (int i = tid; i < HW / 4; i += 448) {
            float4 v = xp[i];
            const int idx = i << 2;
            const int row = idx / 56;
            const int col = idx - row * 56;
            float* d = &lds[(row + 1) * 58 + (col + 1)];
            d[0] = v.x; d[1] = v.y; d[2] = v.z; d[3] = v.w;
        }
        __syncthreads();

        float win[3][9];
        #pragma unroll
        for (int dr = 0; dr < 3; ++dr)
            #pragma unroll
            for (int k = 0; k < 9; ++k)
                win[dr][k] = lds[(r + dr) * 58 + c0 + k];

        const float* wrow = w + (size_t)(co0 * C_ + ci) * 9;
        if (m0) conv_acc7(acc0, win, wrow);
        if (m1) conv_acc7(acc1, win, wrow + (size_t)1 * C_ * 9);
        if (m2) conv_acc7(acc2, win, wrow + (size_t)2 * C_ * 9);
        if (m3) conv_acc7(acc3, win, wrow + (size_t)3 * C_ * 9);
    }

    const int obase = r * 56 + c0;
    auto write_co = [&](int j, int act, const float acc[7]) {
        if (act) {
            float* op = ob + (size_t)(co0 + j) * HW;
            #pragma unroll
            for (int p = 0; p < 7; ++p) op[obase + p] = acc[p];
        } else {
            const float4* s4 = (const float4*)(xb + (size_t)(co0 + j) * HW);
            float4* d4 = (float4*)(ob + (size_t)(co0 + j) * HW);
            for (int i = tid; i < HW / 4; i += 448) d4[i] = s4[i];
        }
    };
    write_co(0, m0, acc0);
    write_co(1, m1, acc1);
    write_co(2, m2, acc2);
    write_co(3, m3, acc3);
}

// ---------------------------------------------------------------------------
extern "C" void kernel_launch(void* const* d_in, const int* in_sizes, int n_in,
                              void* d_out, int out_size, void* d_ws, size_t ws_size,
                              hipStream_t stream) {
    const float* x        = (const float*)d_in[0];
    const float* conv_w   = (const float*)d_in[1];
    const float* cg_w     = (const float*)d_in[2];
    const float* cg_b     = (const float*)d_in[3];
    const float* cg_fcw   = (const float*)d_in[4];
    const float* cg_fcb   = (const float*)d_in[5];
    const float* lg_w     = (const float*)d_in[6];
    const float* lg_b     = (const float*)d_in[7];
    const float* w_ih     = (const float*)d_in[8];
    // d_in[9] = lstm_w_hh: unused by the reference math (only b_hh enters)
    const float* b_ih     = (const float*)d_in[10];
    const float* b_hh     = (const float*)d_in[11];
    const float* lg_fcw   = (const float*)d_in[12];
    const float* lg_fcb   = (const float*)d_in[13];
    float* out = (float*)d_out;

    float* ws     = (float*)d_ws;
    float* g_mean = ws;            // 8192
    float* layer  = ws + 8192;     // 32
    float* cg_s   = ws + 8224;     // 8192
    float* maskp  = ws + 16416;    // 8192
    float* skipf  = ws + 24608;    // 32

    k_mean<<<B_ * C_, 256, 0, stream>>>(x, g_mean);
    k_layer_gate<<<B_, 64, 0, stream>>>(g_mean, lg_w, lg_b, w_ih, b_ih, b_hh,
                                        lg_fcw, lg_fcb, layer);
    k_cg_conv<<<dim3(64, 32), 256, 0, stream>>>(x, cg_w, cg_b, cg_s);
    k_channel_fc<<<B_, 256, 0, stream>>>(cg_s, cg_fcw, cg_fcb, layer, maskp, skipf);
    k_main_conv<<<dim3(64, 32), 448, 0, stream>>>(x, conv_w, maskp, skipf, out);
}

// Round 2
// 1127.252 us; speedup vs baseline: 2.0380x; 2.0380x over previous
//
#include <hip/hip_runtime.h>
#include <math.h>

#define B_     32
#define C_     256
#define H_     56
#define W_     56
#define HW     3136      // 56*56
#define LSTMH  10
#define PSTRIDE 3776     // padded pixel rows per (b, ci-chunk) in xT2 (58*64=3712 used)
#define NT_    14        // n-tiles of 256 (14*256 = 3584 = 56*64)

typedef __attribute__((ext_vector_type(8))) short bf16x8;
typedef __attribute__((ext_vector_type(16))) float f32x16;

__device__ __forceinline__ unsigned short f2bf(float f) {
    unsigned int u = __builtin_bit_cast(unsigned int, f);
    return (unsigned short)((u + 0x7FFFu + ((u >> 16) & 1u)) >> 16);
}

// ---------------------------------------------------------------------------
// K1: per-(b,c) spatial mean of x  -> g_mean[8192]
// ---------------------------------------------------------------------------
__global__ __launch_bounds__(256) void k_mean(const float* __restrict__ x,
                                              float* __restrict__ g_mean) {
    const int plane = blockIdx.x;
    const float4* xp = (const float4*)(x + (size_t)plane * HW);
    float s = 0.f;
    for (int i = threadIdx.x; i < HW / 4; i += 256) {
        float4 v = xp[i];
        s += (v.x + v.y) + (v.z + v.w);
    }
    #pragma unroll
    for (int off = 32; off > 0; off >>= 1) s += __shfl_down(s, off, 64);
    __shared__ float ls[4];
    if ((threadIdx.x & 63) == 0) ls[threadIdx.x >> 6] = s;
    __syncthreads();
    if (threadIdx.x == 0) g_mean[plane] = ((ls[0] + ls[1]) + (ls[2] + ls[3])) / (float)HW;
}

// ---------------------------------------------------------------------------
// K2: layer gate (fp32 exact)
// ---------------------------------------------------------------------------
__global__ __launch_bounds__(64) void k_layer_gate(
        const float* __restrict__ g_mean, const float* __restrict__ lgw,
        const float* __restrict__ lgb, const float* __restrict__ w_ih,
        const float* __restrict__ b_ih, const float* __restrict__ b_hh,
        const float* __restrict__ fcw, const float* __restrict__ fcb,
        float* __restrict__ layer_out) {
    const int b = blockIdx.x;
    __shared__ float g[C_];
    __shared__ float h[LSTMH];
    for (int i = threadIdx.x; i < C_; i += 64) g[i] = g_mean[b * C_ + i];
    __syncthreads();
    if (threadIdx.x < LSTMH) {
        const int j = threadIdx.x;
        float s = lgb[j];
        for (int c = 0; c < C_; ++c) s = fmaf(g[c], lgw[j * C_ + c], s);
        h[j] = fmaxf(s, 0.f);
    }
    __syncthreads();
    if (threadIdx.x == 0) {
        float gates[40];
        #pragma unroll
        for (int k = 0; k < 40; ++k) {
            float s = b_ih[k] + b_hh[k];
            #pragma unroll
            for (int j = 0; j < LSTMH; ++j) s = fmaf(h[j], w_ih[k * LSTMH + j], s);
            gates[k] = s;
        }
        float outv = fcb[0];
        #pragma unroll
        for (int k = 0; k < LSTMH; ++k) {
            float c  = (1.f / (1.f + expf(-gates[k]))) * tanhf(gates[20 + k]);
            float hs = (1.f / (1.f + expf(-gates[30 + k]))) * tanhf(c);
            outv = fmaf(hs, fcw[k], outv);
        }
        outv = fmaxf(outv, 0.f);
        layer_out[b] = rintf(1.f / (1.f + expf(-outv)));
    }
}

// ---------------------------------------------------------------------------
// K3: channel-gate conv (fp32 exact), double-buffered LDS, 8 co per block
// grid = (32 cog, 32 b), 256 threads
// ---------------------------------------------------------------------------
__global__ __launch_bounds__(256) void k_cg_conv(
        const float* __restrict__ x, const float* __restrict__ w,
        const float* __restrict__ bias, float* __restrict__ cg_s) {
    __shared__ float pl[2][HW];
    __shared__ float red[32];
    const int b = blockIdx.y, cog = blockIdx.x, tid = threadIdx.x;
    const int co0 = cog * 8;
    const int i0 = tid, i1 = tid + 256, i2 = tid + 512;
    const int oh0 = i0 / 27, ow0 = i0 - oh0 * 27;
    const int oh1 = i1 / 27, ow1 = i1 - oh1 * 27;
    const int has2 = (i2 < 729);
    const int oh2 = has2 ? (i2 / 27) : 0;
    const int ow2 = has2 ? (i2 - (i2 / 27) * 27) : 0;

    float acc[8][3];
    #pragma unroll
    for (int j = 0; j < 8; ++j) { acc[j][0] = 0.f; acc[j][1] = 0.f; acc[j][2] = 0.f; }
    const float* xb = x + (size_t)b * C_ * HW;

    // prologue: stage ci=0
    {
        const float4* xp = (const float4*)xb;
        float4* d = (float4*)pl[0];
        #pragma unroll
        for (int i = 0; i < 3; ++i) d[tid + i * 256] = xp[tid + i * 256];
        if (tid < 16) d[tid + 768] = xp[tid + 768];
    }
    __syncthreads();

    for (int ci = 0; ci < C_; ++ci) {
        float4 r4[4];
        if (ci < C_ - 1) {
            const float4* xp = (const float4*)(xb + (size_t)(ci + 1) * HW);
            #pragma unroll
            for (int i = 0; i < 3; ++i) r4[i] = xp[tid + i * 256];
            if (tid < 16) r4[3] = xp[tid + 768];
        }
        const float* plane = pl[ci & 1];
        float win0[9], win1[9], win2[9];
        #pragma unroll
        for (int dr = 0; dr < 3; ++dr)
            #pragma unroll
            for (int dc = 0; dc < 3; ++dc) {
                win0[dr * 3 + dc] = plane[(2 * oh0 + dr) * W_ + 2 * ow0 + dc];
                win1[dr * 3 + dc] = plane[(2 * oh1 + dr) * W_ + 2 * ow1 + dc];
                win2[dr * 3 + dc] = has2 ? plane[(2 * oh2 + dr) * W_ + 2 * ow2 + dc] : 0.f;
            }
        const float* wrow = w + (size_t)(co0 * C_ + ci) * 9;
        #pragma unroll
        for (int j = 0; j < 8; ++j) {
            const float* wt = wrow + (size_t)j * C_ * 9;
            float w9[9];
            #pragma unroll
            for (int t = 0; t < 9; ++t) w9[t] = wt[t];
            #pragma unroll
            for (int t = 0; t < 9; ++t) {
                acc[j][0] = fmaf(win0[t], w9[t], acc[j][0]);
                acc[j][1] = fmaf(win1[t], w9[t], acc[j][1]);
                acc[j][2] = fmaf(win2[t], w9[t], acc[j][2]);
            }
        }
        if (ci < C_ - 1) {
            float4* d = (float4*)pl[(ci + 1) & 1];
            #pragma unroll
            for (int i = 0; i < 3; ++i) d[tid + i * 256] = r4[i];
            if (tid < 16) d[tid + 768] = r4[3];
        }
        __syncthreads();
    }

    #pragma unroll
    for (int j = 0; j < 8; ++j) {
        const float bi = bias[co0 + j];
        float s = fmaxf(acc[j][0] + bi, 0.f) + fmaxf(acc[j][1] + bi, 0.f);
        if (has2) s += fmaxf(acc[j][2] + bi, 0.f);
        #pragma unroll
        for (int off = 32; off > 0; off >>= 1) s += __shfl_down(s, off, 64);
        if ((tid & 63) == 0) red[j * 4 + (tid >> 6)] = s;
    }
    __syncthreads();
    if (tid < 8) {
        const int j = tid;
        float t = (red[j * 4] + red[j * 4 + 1]) + (red[j * 4 + 2] + red[j * 4 + 3]);
        cg_s[b * C_ + co0 + j] = t / 729.f;
    }
}

// ---------------------------------------------------------------------------
// K4: channel fc -> effective mask, active-co compaction list
// ---------------------------------------------------------------------------
__global__ __launch_bounds__(256) void k_channel_fc(
        const float* __restrict__ cg_s, const float* __restrict__ fcw,
        const float* __restrict__ fcb, const float* __restrict__ layer,
        float* __restrict__ mask_eff, int* __restrict__ nact,
        int* __restrict__ actlist) {
    const int b = blockIdx.x, co = threadIdx.x;
    __shared__ float g[C_];
    __shared__ float marr[C_];
    __shared__ float cs[4];
    __shared__ int sk_sh;
    g[co] = cg_s[b * C_ + co];
    __syncthreads();
    float s = fcb[co];
    for (int c = 0; c < C_; ++c) s = fmaf(g[c], fcw[co * C_ + c], s);
    const float m = rintf(1.f / (1.f + expf(-fmaxf(s, 0.f))));
    marr[co] = m;
    float cnt = m;
    #pragma unroll
    for (int off = 32; off > 0; off >>= 1) cnt += __shfl_down(cnt, off, 64);
    if ((co & 63) == 0) cs[co >> 6] = cnt;
    __syncthreads();
    if (co == 0) {
        const float total = (cs[0] + cs[1]) + (cs[2] + cs[3]);
        const int skip = (layer[b] < 0.5f || total < 0.5f) ? 1 : 0;
        sk_sh = skip;
        int n = 0;
        int* al = actlist + b * C_;
        if (!skip)
            for (int c = 0; c < C_; ++c)
                if (marr[c] > 0.5f) al[n++] = c;
        nact[b] = n;
        const int pad = (n > 0) ? al[0] : 0;
        for (int i = n; i < C_; ++i) al[i] = pad;
    }
    __syncthreads();
    mask_eff[b * C_ + co] = sk_sh ? 0.f : marr[co];
}

// ---------------------------------------------------------------------------
// K5a: pack weights -> wA[co][ks(16)][tap(9)][cl(16)] bf16
// ---------------------------------------------------------------------------
__global__ __launch_bounds__(256) void k_pack_w(const float* __restrict__ w,
                                                unsigned short* __restrict__ wA) {
    const int co = blockIdx.x;
    for (int d = threadIdx.x; d < 2304; d += 256) {
        const int ks = d / 144, r = d - ks * 144;
        const int tap = r >> 4, cl = r & 15;
        const int ci = ks * 16 + cl;
        wA[(size_t)co * 2304 + d] = f2bf(w[(size_t)co * 2304 + ci * 9 + tap]);
    }
}

// ---------------------------------------------------------------------------
// K5b: pack x -> xT2[b][cc(16)][p(PSTRIDE)][cl(16)] bf16, zero-padded 58x64 grid
// p = prow*64 + pcol; content = x[b][cc*16+cl][prow-1][pcol-1] when in range
// ---------------------------------------------------------------------------
__global__ __launch_bounds__(256) void k_pack_x(const float* __restrict__ x,
                                                unsigned short* __restrict__ xT2) {
    const int b = blockIdx.x >> 4, cc = blockIdx.x & 15;
    for (int p = threadIdx.x; p < PSTRIDE; p += 256) {
        const int prow = p >> 6, pcol = p & 63;
        const int valid = (prow >= 1) && (prow < 57) && (pcol >= 1) && (pcol < 57);
        const float* base = x + ((size_t)(b * C_ + cc * 16) * HW) + (prow - 1) * W_ + (pcol - 1);
        unsigned int d[8];
        #pragma unroll
        for (int t = 0; t < 8; ++t) {
            unsigned short lo = valid ? f2bf(base[(2 * t) * HW]) : 0;
            unsigned short hi = valid ? f2bf(base[(2 * t + 1) * HW]) : 0;
            d[t] = (unsigned int)lo | ((unsigned int)hi << 16);
        }
        uint4* dst = (uint4*)(xT2 + ((size_t)(b * 16 + cc) * PSTRIDE + p) * 16);
        dst[0] = make_uint4(d[0], d[1], d[2], d[3]);
        dst[1] = make_uint4(d[4], d[5], d[6], d[7]);
    }
}

// ---------------------------------------------------------------------------
// K6: copy inactive planes out = x
// ---------------------------------------------------------------------------
__global__ __launch_bounds__(256) void k_copy(const float* __restrict__ x,
                                              const float* __restrict__ mask_eff,
                                              float* __restrict__ out) {
    const int plane = blockIdx.x;
    if (mask_eff[plane] > 0.5f) return;
    const float4* s = (const float4*)(x + (size_t)plane * HW);
    float4* d = (float4*)(out + (size_t)plane * HW);
    const int tid = threadIdx.x;
    #pragma unroll
    for (int i = 0; i < 3; ++i) d[tid + i * 256] = s[tid + i * 256];
    if (tid < 16) d[tid + 768] = s[tid + 768];
}

// ---------------------------------------------------------------------------
// K7: main conv via bf16 MFMA implicit GEMM (9 shifted-tap accumulation).
// Block: 256 thr (4 waves), tile = 64 active-co x 256 padded-pixels.
// Wave: 64co x 64n (2x2 frags of 32), mfma_f32_32x32x16_bf16.
// A (weights, 9 taps x 64co x 16ci) single-buffered LDS; B (x slice) dbuf LDS.
// grid = (4*NT_, 32); blocks with cot*64 >= nact[b] exit.
// ---------------------------------------------------------------------------
#define LDSA 27648            // 9*64*48
#define LDSB 18528            // 386*48
__global__ __launch_bounds__(256, 2) void k_mfma_conv(
        const unsigned short* __restrict__ wA,
        const unsigned short* __restrict__ xT2,
        const int* __restrict__ actlist, const int* __restrict__ nact,
        float* __restrict__ out) {
    __shared__ __align__(16) unsigned char lds[LDSA + 2 * LDSB];
    const int b = blockIdx.y;
    const int na = nact[b];
    const int cot = blockIdx.x & 3;
    const int nt = blockIdx.x >> 2;
    if (cot * 64 >= na) return;

    const int tid = threadIdx.x;
    const int lane = tid & 63, wid = tid >> 6;
    const int ln = lane & 31, lk = lane >> 5;
    const int* al = actlist + b * C_;

    f32x16 acc[2][2];
    #pragma unroll
    for (int i = 0; i < 2; ++i)
        #pragma unroll
        for (int j = 0; j < 2; ++j)
            #pragma unroll
            for (int r = 0; r < 16; ++r) acc[i][j][r] = 0.f;

    // ---- staging helpers (inline) ----
    // A: 1152 16B-units: u -> co_l = u&63, rr = u>>6 (tap = rr>>1, ch = rr&1)
    // B: 772 16B-units:  u -> row = u>>1, ch = u&1 ; source contiguous
    const unsigned short* wAb = wA;
    #define LOAD_A(ksq, ar)                                                          \
        {                                                                            \
            _Pragma("unroll")                                                        \
            for (int i = 0; i < 4; ++i) {                                            \
                const int u = tid + i * 256;                                         \
                const int co_l = u & 63, rr = u >> 6;                                \
                const int cs = al[cot * 64 + co_l];                                  \
                ar[i] = *(const bf16x8*)(wAb + (size_t)cs * 2304 + (ksq) * 144 +     \
                                         (rr >> 1) * 16 + (rr & 1) * 8);             \
            }                                                                        \
            if (tid < 128) {                                                         \
                const int u = tid + 1024;                                            \
                const int co_l = u & 63, rr = u >> 6;                                \
                const int cs = al[cot * 64 + co_l];                                  \
                ar[4] = *(const bf16x8*)(wAb + (size_t)cs * 2304 + (ksq) * 144 +     \
                                         (rr >> 1) * 16 + (rr & 1) * 8);             \
            }                                                                        \
        }
    #define WRITE_A(ar)                                                              \
        {                                                                            \
            _Pragma("unroll")                                                        \
            for (int i = 0; i < 4; ++i) {                                            \
                const int u = tid + i * 256;                                         \
                const int co_l = u & 63, rr = u >> 6;                                \
                *(bf16x8*)(lds + (rr >> 1) * 3072 + co_l * 48 + (rr & 1) * 16) = ar[i]; \
            }                                                                        \
            if (tid < 128) {                                                         \
                const int u = tid + 1024;                                            \
                const int co_l = u & 63, rr = u >> 6;                                \
                *(bf16x8*)(lds + (rr >> 1) * 3072 + co_l * 48 + (rr & 1) * 16) = ar[4]; \
            }                                                                        \
        }
    #define LOAD_B(ksq, br)                                                          \
        {                                                                            \
            const unsigned short* src = xT2 +                                        \
                ((size_t)(b * 16 + (ksq)) * PSTRIDE + nt * 256) * 16;                \
            _Pragma("unroll")                                                        \
            for (int i = 0; i < 3; ++i) br[i] = *(const bf16x8*)(src + (tid + i * 256) * 8); \
            if (tid < 4) br[3] = *(const bf16x8*)(src + (tid + 768) * 8);            \
        }
    #define WRITE_B(br, buf)                                                         \
        {                                                                            \
            unsigned char* dst = lds + LDSA + (buf) * LDSB;                          \
            _Pragma("unroll")                                                        \
            for (int i = 0; i < 3; ++i) {                                            \
                const int u = tid + i * 256;                                         \
                *(bf16x8*)(dst + (u >> 1) * 48 + (u & 1) * 16) = br[i];              \
            }                                                                        \
            if (tid < 4) {                                                           \
                const int u = tid + 768;                                             \
                *(bf16x8*)(dst + (u >> 1) * 48 + (u & 1) * 16) = br[3];              \
            }                                                                        \
        }

    // prologue: stage kstep 0
    {
        bf16x8 ar[5]; bf16x8 br[4];
        LOAD_A(0, ar); LOAD_B(0, br);
        WRITE_A(ar); WRITE_B(br, 0);
    }
    __syncthreads();

    const unsigned char* abase = lds + ln * 48 + lk * 16;
    const unsigned char* bb0 = lds + LDSA + (wid * 64 + ln) * 48 + lk * 16;

    for (int k = 0; k < 16; ++k) {
        bf16x8 ar[5]; bf16x8 br[4];
        if (k < 15) { LOAD_B(k + 1, br); LOAD_A(k + 1, ar); }

        const unsigned char* bbase = bb0 + (k & 1) * LDSB;
        #pragma unroll
        for (int tap = 0; tap < 9; ++tap) {
            const int off = (tap / 3) * 64 + (tap % 3);
            bf16x8 a0 = *(const bf16x8*)(abase + tap * 3072);
            bf16x8 a1 = *(const bf16x8*)(abase + tap * 3072 + 32 * 48);
            bf16x8 b0 = *(const bf16x8*)(bbase + off * 48);
            bf16x8 b1 = *(const bf16x8*)(bbase + (off + 32) * 48);
            acc[0][0] = __builtin_amdgcn_mfma_f32_32x32x16_bf16(a0, b0, acc[0][0], 0, 0, 0);
            acc[0][1] = __builtin_amdgcn_mfma_f32_32x32x16_bf16(a0, b1, acc[0][1], 0, 0, 0);
            acc[1][0] = __builtin_amdgcn_mfma_f32_32x32x16_bf16(a1, b0, acc[1][0], 0, 0, 0);
            acc[1][1] = __builtin_amdgcn_mfma_f32_32x32x16_bf16(a1, b1, acc[1][1], 0, 0, 0);
        }
        __syncthreads();
        if (k < 15) { WRITE_A(ar); WRITE_B(br, (k + 1) & 1); }
        __syncthreads();
    }

    // epilogue: C/D layout col=lane&31 (n), row=(reg&3)+8*(reg>>2)+4*(lane>>5) (co)
    const int p_base = nt * 256 + wid * 64 + ln;
    float* ob = out + (size_t)b * C_ * HW;
    #pragma unroll
    for (int i = 0; i < 2; ++i)
        #pragma unroll
        for (int j = 0; j < 2; ++j) {
            const int p = p_base + j * 32;
            const int c = p & 63;
            if (c >= 56) continue;
            const int opix = (p >> 6) * 56 + c;
            #pragma unroll
            for (int r = 0; r < 16; ++r) {
                const int row = (r & 3) + 8 * (r >> 2) + 4 * lk;
                const int co_idx = cot * 64 + i * 32 + row;
                if (co_idx < na) {
                    const int co = al[co_idx];
                    ob[(size_t)co * HW + opix] = acc[i][j][r];
                }
            }
        }
    #undef LOAD_A
    #undef WRITE_A
    #undef LOAD_B
    #undef WRITE_B
}

// ---------------------------------------------------------------------------
// Fallback fp32 main conv (used only if ws too small for bf16 packs)
// ---------------------------------------------------------------------------
__device__ __forceinline__ void conv_acc7(float acc[7], const float win[3][9],
                                          const float* __restrict__ wt) {
    float w9[9];
    #pragma unroll
    for (int t = 0; t < 9; ++t) w9[t] = wt[t];
    #pragma unroll
    for (int p = 0; p < 7; ++p) {
        float s = acc[p];
        #pragma unroll
        for (int dr = 0; dr < 3; ++dr)
            #pragma unroll
            for (int dk = 0; dk < 3; ++dk)
                s = fmaf(win[dr][p + dk], w9[dr * 3 + dk], s);
        acc[p] = s;
    }
}

__global__ __launch_bounds__(448) void k_main_conv_fb(
        const float* __restrict__ x, const float* __restrict__ w,
        const float* __restrict__ mask_eff, float* __restrict__ out) {
    __shared__ float lds[58 * 58];
    const int b = blockIdx.y, cog = blockIdx.x, tid = threadIdx.x;
    const int co0 = cog * 4;
    const float* xb = x + (size_t)b * C_ * HW;
    float* ob = out + (size_t)b * C_ * HW;

    int m0 = (mask_eff[b * C_ + co0 + 0] > 0.5f) ? 1 : 0;
    int m1 = (mask_eff[b * C_ + co0 + 1] > 0.5f) ? 1 : 0;
    int m2 = (mask_eff[b * C_ + co0 + 2] > 0.5f) ? 1 : 0;
    int m3 = (mask_eff[b * C_ + co0 + 3] > 0.5f) ? 1 : 0;
    m0 = __builtin_amdgcn_readfirstlane(m0);
    m1 = __builtin_amdgcn_readfirstlane(m1);
    m2 = __builtin_amdgcn_readfirstlane(m2);
    m3 = __builtin_amdgcn_readfirstlane(m3);

    if (!(m0 | m1 | m2 | m3)) {
        const float4* s4 = (const float4*)(xb + (size_t)co0 * HW);
        float4* d4 = (float4*)(ob + (size_t)co0 * HW);
        for (int i = tid; i < 4 * (HW / 4); i += 448) d4[i] = s4[i];
        return;
    }
    for (int i = tid; i < 58 * 58; i += 448) lds[i] = 0.f;

    const int r = tid >> 3;
    const int c0 = (tid & 7) * 7;
    float acc0[7] = {}, acc1[7] = {}, acc2[7] = {}, acc3[7] = {};

    for (int ci = 0; ci < C_; ++ci) {
        __syncthreads();
        const float4* xp = (const float4*)(xb + (size_t)ci * HW);
        for (int i = tid; i < HW / 4; i += 448) {
            float4 v = xp[i];
            const int idx = i << 2;
            const int row = idx / 56;
            const int col = idx - row * 56;
            float* d = &lds[(row + 1) * 58 + (col + 1)];
            d[0] = v.x; d[1] = v.y; d[2] = v.z; d[3] = v.w;
        }
        __syncthreads();
        float win[3][9];
        #pragma unroll
        for (int dr = 0; dr < 3; ++dr)
            #pragma unroll
            for (int kk = 0; kk < 9; ++kk)
                win[dr][kk] = lds[(r + dr) * 58 + c0 + kk];
        const float* wrow = w + (size_t)(co0 * C_ + ci) * 9;
        if (m0) conv_acc7(acc0, win, wrow);
        if (m1) conv_acc7(acc1, win, wrow + (size_t)1 * C_ * 9);
        if (m2) conv_acc7(acc2, win, wrow + (size_t)2 * C_ * 9);
        if (m3) conv_acc7(acc3, win, wrow + (size_t)3 * C_ * 9);
    }
    const int obase = r * 56 + c0;
    auto write_co = [&](int j, int act, const float acc[7]) {
        if (act) {
            float* op = ob + (size_t)(co0 + j) * HW;
            #pragma unroll
            for (int p = 0; p < 7; ++p) op[obase + p] = acc[p];
        } else {
            const float4* s4 = (const float4*)(xb + (size_t)(co0 + j) * HW);
            float4* d4 = (float4*)(ob + (size_t)(co0 + j) * HW);
            for (int i = tid; i < HW / 4; i += 448) d4[i] = s4[i];
        }
    };
    write_co(0, m0, acc0);
    write_co(1, m1, acc1);
    write_co(2, m2, acc2);
    write_co(3, m3, acc3);
}

// ---------------------------------------------------------------------------
extern "C" void kernel_launch(void* const* d_in, const int* in_sizes, int n_in,
                              void* d_out, int out_size, void* d_ws, size_t ws_size,
                              hipStream_t stream) {
    const float* x      = (const float*)d_in[0];
    const float* conv_w = (const float*)d_in[1];
    const float* cg_w   = (const float*)d_in[2];
    const float* cg_b   = (const float*)d_in[3];
    const float* cg_fcw = (const float*)d_in[4];
    const float* cg_fcb = (const float*)d_in[5];
    const float* lg_w   = (const float*)d_in[6];
    const float* lg_b   = (const float*)d_in[7];
    const float* w_ih   = (const float*)d_in[8];
    // d_in[9] = lstm_w_hh: unused (h_prev = 0 in reference)
    const float* b_ih   = (const float*)d_in[10];
    const float* b_hh   = (const float*)d_in[11];
    const float* lg_fcw = (const float*)d_in[12];
    const float* lg_fcb = (const float*)d_in[13];
    float* out = (float*)d_out;

    char* ws = (char*)d_ws;
    float* g_mean   = (float*)(ws + 0);        // 32768 B
    float* cg_s     = (float*)(ws + 32768);    // 32768 B
    float* mask_eff = (float*)(ws + 65536);    // 32768 B
    float* layer    = (float*)(ws + 98304);    // 128 B
    int*   nact     = (int*)  (ws + 98432);    // 128 B
    int*   actlist  = (int*)  (ws + 98560);    // 32768 B
    unsigned short* wA  = (unsigned short*)(ws + 131584);   // 1,179,648 B
    unsigned short* xT2 = (unsigned short*)(ws + 1311232);  // 61,865,984 B
    const size_t WS_NEEDED = 1311232 + (size_t)32 * 16 * PSTRIDE * 16 * 2;

    const bool mfma_path = (ws_size >= WS_NEEDED);

    k_mean<<<B_ * C_, 256, 0, stream>>>(x, g_mean);
    k_layer_gate<<<B_, 64, 0, stream>>>(g_mean, lg_w, lg_b, w_ih, b_ih, b_hh,
                                        lg_fcw, lg_fcb, layer);
    k_cg_conv<<<dim3(32, 32), 256, 0, stream>>>(x, cg_w, cg_b, cg_s);
    k_channel_fc<<<B_, 256, 0, stream>>>(cg_s, cg_fcw, cg_fcb, layer,
                                         mask_eff, nact, actlist);
    if (mfma_path) {
        k_pack_w<<<C_, 256, 0, stream>>>(conv_w, wA);
        k_pack_x<<<B_ * 16, 256, 0, stream>>>(x, xT2);
        k_copy<<<B_ * C_, 256, 0, stream>>>(x, mask_eff, out);
        k_mfma_conv<<<dim3(4 * NT_, B_), 256, 0, stream>>>(wA, xT2, actlist, nact, out);
    } else {
        k_main_conv_fb<<<dim3(64, 32), 448, 0, stream>>>(x, conv_w, mask_eff, out);
    }
}

// Round 3
// 639.199 us; speedup vs baseline: 3.5941x; 1.7635x over previous
//
#include <hip/hip_runtime.h>
#include <math.h>

#define B_     32
#define C_     256
#define H_     56
#define W_     56
#define HW     3136      // 56*56
#define LSTMH  10
#define PSTRIDE 3776     // padded pixel rows per (b, ci-chunk) in xT2 (58*64=3712 used)
#define NT_    14        // main-conv n-tiles of 256 (14*256 = 3584 = 56*64)

typedef __attribute__((ext_vector_type(8))) short bf16x8;
typedef __attribute__((ext_vector_type(16))) float f32x16;

__device__ __forceinline__ unsigned short f2bf(float f) {
    unsigned int u = __builtin_bit_cast(unsigned int, f);
    return (unsigned short)((u + 0x7FFFu + ((u >> 16) & 1u)) >> 16);
}
__device__ __forceinline__ float bf2f(unsigned short h) {
    unsigned int u = ((unsigned int)h) << 16;
    return __builtin_bit_cast(float, u);
}

// ---------------------------------------------------------------------------
// K1: per-(b,c) spatial mean of x  -> g_mean[8192]
// ---------------------------------------------------------------------------
__global__ __launch_bounds__(256) void k_mean(const float* __restrict__ x,
                                              float* __restrict__ g_mean) {
    const int plane = blockIdx.x;
    const float4* xp = (const float4*)(x + (size_t)plane * HW);
    float s = 0.f;
    for (int i = threadIdx.x; i < HW / 4; i += 256) {
        float4 v = xp[i];
        s += (v.x + v.y) + (v.z + v.w);
    }
    #pragma unroll
    for (int off = 32; off > 0; off >>= 1) s += __shfl_down(s, off, 64);
    __shared__ float ls[4];
    if ((threadIdx.x & 63) == 0) ls[threadIdx.x >> 6] = s;
    __syncthreads();
    if (threadIdx.x == 0) g_mean[plane] = ((ls[0] + ls[1]) + (ls[2] + ls[3])) / (float)HW;
}

// ---------------------------------------------------------------------------
// K2: layer gate (fp32 exact)
// ---------------------------------------------------------------------------
__global__ __launch_bounds__(64) void k_layer_gate(
        const float* __restrict__ g_mean, const float* __restrict__ lgw,
        const float* __restrict__ lgb, const float* __restrict__ w_ih,
        const float* __restrict__ b_ih, const float* __restrict__ b_hh,
        const float* __restrict__ fcw, const float* __restrict__ fcb,
        float* __restrict__ layer_out) {
    const int b = blockIdx.x;
    __shared__ float g[C_];
    __shared__ float h[LSTMH];
    for (int i = threadIdx.x; i < C_; i += 64) g[i] = g_mean[b * C_ + i];
    __syncthreads();
    if (threadIdx.x < LSTMH) {
        const int j = threadIdx.x;
        float s = lgb[j];
        for (int c = 0; c < C_; ++c) s = fmaf(g[c], lgw[j * C_ + c], s);
        h[j] = fmaxf(s, 0.f);
    }
    __syncthreads();
    if (threadIdx.x == 0) {
        float gates[40];
        #pragma unroll
        for (int k = 0; k < 40; ++k) {
            float s = b_ih[k] + b_hh[k];
            #pragma unroll
            for (int j = 0; j < LSTMH; ++j) s = fmaf(h[j], w_ih[k * LSTMH + j], s);
            gates[k] = s;
        }
        float outv = fcb[0];
        #pragma unroll
        for (int k = 0; k < LSTMH; ++k) {
            float c  = (1.f / (1.f + expf(-gates[k]))) * tanhf(gates[20 + k]);
            float hs = (1.f / (1.f + expf(-gates[30 + k]))) * tanhf(c);
            outv = fmaf(hs, fcw[k], outv);
        }
        outv = fmaxf(outv, 0.f);
        layer_out[b] = rintf(1.f / (1.f + expf(-outv)));
    }
}

// ---------------------------------------------------------------------------
// K3 (fallback only): channel-gate conv fp32, writes MEAN to cg_s
// ---------------------------------------------------------------------------
__global__ __launch_bounds__(256) void k_cg_conv(
        const float* __restrict__ x, const float* __restrict__ w,
        const float* __restrict__ bias, float* __restrict__ cg_s) {
    __shared__ float pl[2][HW];
    __shared__ float red[32];
    const int b = blockIdx.y, cog = blockIdx.x, tid = threadIdx.x;
    const int co0 = cog * 8;
    const int i0 = tid, i1 = tid + 256, i2 = tid + 512;
    const int oh0 = i0 / 27, ow0 = i0 - oh0 * 27;
    const int oh1 = i1 / 27, ow1 = i1 - oh1 * 27;
    const int has2 = (i2 < 729);
    const int oh2 = has2 ? (i2 / 27) : 0;
    const int ow2 = has2 ? (i2 - (i2 / 27) * 27) : 0;

    float acc[8][3];
    #pragma unroll
    for (int j = 0; j < 8; ++j) { acc[j][0] = 0.f; acc[j][1] = 0.f; acc[j][2] = 0.f; }
    const float* xb = x + (size_t)b * C_ * HW;
    {
        const float4* xp = (const float4*)xb;
        float4* d = (float4*)pl[0];
        #pragma unroll
        for (int i = 0; i < 3; ++i) d[tid + i * 256] = xp[tid + i * 256];
        if (tid < 16) d[tid + 768] = xp[tid + 768];
    }
    __syncthreads();
    for (int ci = 0; ci < C_; ++ci) {
        float4 r4[4];
        if (ci < C_ - 1) {
            const float4* xp = (const float4*)(xb + (size_t)(ci + 1) * HW);
            #pragma unroll
            for (int i = 0; i < 3; ++i) r4[i] = xp[tid + i * 256];
            if (tid < 16) r4[3] = xp[tid + 768];
        }
        const float* plane = pl[ci & 1];
        float win0[9], win1[9], win2[9];
        #pragma unroll
        for (int dr = 0; dr < 3; ++dr)
            #pragma unroll
            for (int dc = 0; dc < 3; ++dc) {
                win0[dr * 3 + dc] = plane[(2 * oh0 + dr) * W_ + 2 * ow0 + dc];
                win1[dr * 3 + dc] = plane[(2 * oh1 + dr) * W_ + 2 * ow1 + dc];
                win2[dr * 3 + dc] = has2 ? plane[(2 * oh2 + dr) * W_ + 2 * ow2 + dc] : 0.f;
            }
        const float* wrow = w + (size_t)(co0 * C_ + ci) * 9;
        #pragma unroll
        for (int j = 0; j < 8; ++j) {
            const float* wt = wrow + (size_t)j * C_ * 9;
            float w9[9];
            #pragma unroll
            for (int t = 0; t < 9; ++t) w9[t] = wt[t];
            #pragma unroll
            for (int t = 0; t < 9; ++t) {
                acc[j][0] = fmaf(win0[t], w9[t], acc[j][0]);
                acc[j][1] = fmaf(win1[t], w9[t], acc[j][1]);
                acc[j][2] = fmaf(win2[t], w9[t], acc[j][2]);
            }
        }
        if (ci < C_ - 1) {
            float4* d = (float4*)pl[(ci + 1) & 1];
            #pragma unroll
            for (int i = 0; i < 3; ++i) d[tid + i * 256] = r4[i];
            if (tid < 16) d[tid + 768] = r4[3];
        }
        __syncthreads();
    }
    #pragma unroll
    for (int j = 0; j < 8; ++j) {
        const float bi = bias[co0 + j];
        float s = fmaxf(acc[j][0] + bi, 0.f) + fmaxf(acc[j][1] + bi, 0.f);
        if (has2) s += fmaxf(acc[j][2] + bi, 0.f);
        #pragma unroll
        for (int off = 32; off > 0; off >>= 1) s += __shfl_down(s, off, 64);
        if ((tid & 63) == 0) red[j * 4 + (tid >> 6)] = s;
    }
    __syncthreads();
    if (tid < 8) {
        const int j = tid;
        float t = (red[j * 4] + red[j * 4 + 1]) + (red[j * 4 + 2] + red[j * 4 + 3]);
        cg_s[b * C_ + co0 + j] = t / 729.f;
    }
}

// ---------------------------------------------------------------------------
// K4: channel fc -> effective mask, active-co compaction list
// scale: cg_s is SUM (mfma path, scale=1/729) or MEAN (fallback, scale=1)
// ---------------------------------------------------------------------------
__global__ __launch_bounds__(256) void k_channel_fc(
        const float* __restrict__ cg_s, const float* __restrict__ fcw,
        const float* __restrict__ fcb, const float* __restrict__ layer,
        float* __restrict__ mask_eff, int* __restrict__ nact,
        int* __restrict__ actlist, float scale) {
    const int b = blockIdx.x, co = threadIdx.x;
    __shared__ float g[C_];
    __shared__ float marr[C_];
    __shared__ float cs[4];
    __shared__ int sk_sh;
    g[co] = cg_s[b * C_ + co] * scale;
    __syncthreads();
    float s = fcb[co];
    for (int c = 0; c < C_; ++c) s = fmaf(g[c], fcw[co * C_ + c], s);
    const float m = rintf(1.f / (1.f + expf(-fmaxf(s, 0.f))));
    marr[co] = m;
    float cnt = m;
    #pragma unroll
    for (int off = 32; off > 0; off >>= 1) cnt += __shfl_down(cnt, off, 64);
    if ((co & 63) == 0) cs[co >> 6] = cnt;
    __syncthreads();
    if (co == 0) {
        const float total = (cs[0] + cs[1]) + (cs[2] + cs[3]);
        const int skip = (layer[b] < 0.5f || total < 0.5f) ? 1 : 0;
        sk_sh = skip;
        int n = 0;
        int* al = actlist + b * C_;
        if (!skip)
            for (int c = 0; c < C_; ++c)
                if (marr[c] > 0.5f) al[n++] = c;
        nact[b] = n;
        const int pad = (n > 0) ? al[0] : 0;
        for (int i = n; i < C_; ++i) al[i] = pad;
    }
    __syncthreads();
    mask_eff[b * C_ + co] = sk_sh ? 0.f : marr[co];
}

// ---------------------------------------------------------------------------
// K5a: pack main-conv weights -> wA[co][ks16][tap9][cl16] bf16
// ---------------------------------------------------------------------------
__global__ __launch_bounds__(256) void k_pack_w(const float* __restrict__ w,
                                                unsigned short* __restrict__ wA) {
    const int co = blockIdx.x;
    for (int d = threadIdx.x; d < 2304; d += 256) {
        const int ks = d / 144, r = d - ks * 144;
        const int tap = r >> 4, cl = r & 15;
        const int ci = ks * 16 + cl;
        wA[(size_t)co * 2304 + d] = f2bf(w[(size_t)co * 2304 + ci * 9 + tap]);
    }
}

// ---------------------------------------------------------------------------
// K5a': pack cg weights hi/lo -> same layout
// ---------------------------------------------------------------------------
__global__ __launch_bounds__(256) void k_pack_wg(const float* __restrict__ w,
                                                 unsigned short* __restrict__ whi,
                                                 unsigned short* __restrict__ wlo) {
    const int co = blockIdx.x;
    for (int d = threadIdx.x; d < 2304; d += 256) {
        const int ks = d / 144, r = d - ks * 144;
        const int tap = r >> 4, cl = r & 15;
        const int ci = ks * 16 + cl;
        const float v = w[(size_t)co * 2304 + ci * 9 + tap];
        const unsigned short h = f2bf(v);
        whi[(size_t)co * 2304 + d] = h;
        wlo[(size_t)co * 2304 + d] = f2bf(v - bf2f(h));
    }
}

// ---------------------------------------------------------------------------
// K5b: pack x -> xT2 (hi) and xT2lo (residual), zero-padded 58x64 grid
// layout [b][cc16][p PSTRIDE][cl16]; p = prow*64+pcol; src x[cc*16+cl][prow-1][pcol-1]
// ---------------------------------------------------------------------------
__global__ __launch_bounds__(256) void k_pack_x(const float* __restrict__ x,
                                                unsigned short* __restrict__ xhi,
                                                unsigned short* __restrict__ xlo,
                                                int write_lo) {
    const int b = blockIdx.x >> 4, cc = blockIdx.x & 15;
    for (int p = threadIdx.x; p < PSTRIDE; p += 256) {
        const int prow = p >> 6, pcol = p & 63;
        const int valid = (prow >= 1) && (prow < 57) && (pcol >= 1) && (pcol < 57);
        const float* base = x + ((size_t)(b * C_ + cc * 16) * HW) + (prow - 1) * W_ + (pcol - 1);
        unsigned int dh[8], dl[8];
        #pragma unroll
        for (int t = 0; t < 8; ++t) {
            float v0 = valid ? base[(2 * t) * HW] : 0.f;
            float v1 = valid ? base[(2 * t + 1) * HW] : 0.f;
            unsigned short h0 = f2bf(v0), h1 = f2bf(v1);
            unsigned short l0 = f2bf(v0 - bf2f(h0)), l1 = f2bf(v1 - bf2f(h1));
            dh[t] = (unsigned int)h0 | ((unsigned int)h1 << 16);
            dl[t] = (unsigned int)l0 | ((unsigned int)l1 << 16);
        }
        uint4* dsth = (uint4*)(xhi + ((size_t)(b * 16 + cc) * PSTRIDE + p) * 16);
        dsth[0] = make_uint4(dh[0], dh[1], dh[2], dh[3]);
        dsth[1] = make_uint4(dh[4], dh[5], dh[6], dh[7]);
        if (write_lo) {
            uint4* dstl = (uint4*)(xlo + ((size_t)(b * 16 + cc) * PSTRIDE + p) * 16);
            dstl[0] = make_uint4(dl[0], dl[1], dl[2], dl[3]);
            dstl[1] = make_uint4(dl[4], dl[5], dl[6], dl[7]);
        }
    }
}

// ---------------------------------------------------------------------------
// K_cg_mfma: channel-gate conv via split-bf16 MFMA (3-product: WhXh+WhXl+WlXh).
// Stride-2 conv as unit-stride GEMM via phase-split (space-to-depth):
//   out(oh,ow) tap(dr,dc) reads phase(dr&1,dc&1) image at (oh+(dr>>1), ow+(dc>>1)).
// Block: 256 thr (4 waves), tile = 32 co x 256 linear-n pixels (n=oh*27+ow).
// 32 iters: bsel = it>>4 (Xhi then Xlo pass), ks = it&15 (16-ci chunk).
// Fused relu+bias+sum epilogue -> atomicAdd into cg_s (SUM over 729 pixels).
// LDS (57856 B, conflict-free kh-split layout):
//   A [kh2][sel2][tap9][co32]x16B = 18432 ; B [kh2][ph4][rl11][c28]x16B = 39424
// ---------------------------------------------------------------------------
#define CG_LDSA 18432
#define CG_LDSB 39424
__global__ __launch_bounds__(256, 2) void k_cg_mfma(
        const unsigned short* __restrict__ wg_hi,
        const unsigned short* __restrict__ wg_lo,
        const unsigned short* __restrict__ x_hi,
        const unsigned short* __restrict__ x_lo,
        const float* __restrict__ bias,
        float* __restrict__ cg_s) {
    __shared__ __align__(16) unsigned char lds[CG_LDSA + CG_LDSB];
    __shared__ float cg_part[32];
    const int b = blockIdx.y;
    const int cot = blockIdx.x & 7;     // 8 co-tiles of 32
    const int nt = blockIdx.x >> 3;     // 3 n-tiles of 256
    const int tid = threadIdx.x;
    const int lane = tid & 63, wid = tid >> 6;
    const int ln = lane & 31, lk = lane >> 5;
    const int n0 = nt * 256;
    const int r0 = n0 / 27;

    // per-lane pixel coords for the 2 n-frags
    int valid[2], bbase[2];
    #pragma unroll
    for (int j = 0; j < 2; ++j) {
        const int n = n0 + wid * 64 + j * 32 + ln;
        valid[j] = (n < 729);
        const int nc = valid[j] ? n : 728;
        const int oh = nc / 27, ow = nc - 27 * oh;
        bbase[j] = CG_LDSA + lk * (CG_LDSB / 2) + ((oh - r0) * 28 + ow) * 16;
    }
    if (tid < 32) cg_part[tid] = 0.f;

    f32x16 acc[2];
    #pragma unroll
    for (int j = 0; j < 2; ++j)
        #pragma unroll
        for (int r = 0; r < 16; ++r) acc[j][r] = 0.f;

    // precompute staging offsets (loop-invariant)
    int a_src[5], a_lds[5];   // a_src: offset within wg (minus ks*144 term); sel via sign trick
    int a_sel[5], a_ok[5];
    #pragma unroll
    for (int i = 0; i < 5; ++i) {
        const int u = tid + i * 256;
        a_ok[i] = (u < 1152);
        const int kh = (u >= 576) ? 1 : 0;
        const int row = u - kh * 576;
        const int col = row & 31;
        const int v = row >> 5;            // 0..17
        const int tap = v % 9;
        a_sel[i] = v / 9;
        a_src[i] = (cot * 32 + col) * 2304 + tap * 16 + kh * 8;
        a_lds[i] = kh * (CG_LDSA / 2) + ((a_sel[i] * 9 + tap) * 32 + col) * 16;
    }
    int b_src[10], b_lds[10], b_ok[10];
    #pragma unroll
    for (int i = 0; i < 10; ++i) {
        const int u = tid + i * 256;
        b_ok[i] = (u < 2464);
        const int kh = (u >= 1232) ? 1 : 0;
        const int row = u - kh * 1232;
        const int c = row % 28;
        const int v = row / 28;            // 0..43
        const int rl = v % 11, ph = v / 11;
        const int pr = ph >> 1, pc = ph & 1;
        int prow = 2 * (r0 + rl) + pr + 1;
        if (prow > 57) prow = 57;
        const int pcol = 2 * c + pc + 1;
        b_src[i] = (prow * 64 + pcol) * 16 + kh * 8;
        b_lds[i] = CG_LDSA + kh * (CG_LDSB / 2) + ((ph * 11 + rl) * 28 + c) * 16;
    }

    for (int it = 0; it < 32; ++it) {
        const int bsel = it >> 4;
        const int ks = it & 15;
        const unsigned short* xs = bsel ? x_lo : x_hi;
        const size_t bchunk = ((size_t)(b * 16 + ks)) * PSTRIDE * 16;

        bf16x8 areg[5], breg[10];
        #pragma unroll
        for (int i = 0; i < 5; ++i)
            if (a_ok[i]) {
                const unsigned short* wg = a_sel[i] ? wg_lo : wg_hi;
                areg[i] = *(const bf16x8*)(wg + a_src[i] + ks * 144);
            }
        #pragma unroll
        for (int i = 0; i < 10; ++i)
            if (b_ok[i]) breg[i] = *(const bf16x8*)(xs + bchunk + b_src[i]);

        __syncthreads();   // previous iteration's LDS reads complete
        #pragma unroll
        for (int i = 0; i < 5; ++i)
            if (a_ok[i]) *(bf16x8*)(lds + a_lds[i]) = areg[i];
        #pragma unroll
        for (int i = 0; i < 10; ++i)
            if (b_ok[i]) *(bf16x8*)(lds + b_lds[i]) = breg[i];
        __syncthreads();

        #pragma unroll
        for (int tap = 0; tap < 9; ++tap) {
            const int dr = tap / 3, dc = tap % 3;
            const int ph = (dr & 1) * 2 + (dc & 1);
            const int boff = (ph * 308 + (dr >> 1) * 28 + (dc >> 1)) * 16;
            bf16x8 b0 = *(const bf16x8*)(lds + bbase[0] + boff);
            bf16x8 b1 = *(const bf16x8*)(lds + bbase[1] + boff);
            bf16x8 ahi = *(const bf16x8*)(lds + lk * (CG_LDSA / 2) + (tap * 32 + ln) * 16);
            acc[0] = __builtin_amdgcn_mfma_f32_32x32x16_bf16(ahi, b0, acc[0], 0, 0, 0);
            acc[1] = __builtin_amdgcn_mfma_f32_32x32x16_bf16(ahi, b1, acc[1], 0, 0, 0);
            if (bsel == 0) {
                bf16x8 alo = *(const bf16x8*)(lds + lk * (CG_LDSA / 2) + ((9 + tap) * 32 + ln) * 16);
                acc[0] = __builtin_amdgcn_mfma_f32_32x32x16_bf16(alo, b0, acc[0], 0, 0, 0);
                acc[1] = __builtin_amdgcn_mfma_f32_32x32x16_bf16(alo, b1, acc[1], 0, 0, 0);
            }
        }
    }

    // epilogue: relu(acc + bias), masked sum over valid pixels, reduce to cg_s
    #pragma unroll
    for (int r = 0; r < 16; ++r) {
        const int row = (r & 3) + 8 * (r >> 2) + 4 * lk;
        const float bi = bias[cot * 32 + row];
        float s = 0.f;
        if (valid[0]) s += fmaxf(acc[0][r] + bi, 0.f);
        if (valid[1]) s += fmaxf(acc[1][r] + bi, 0.f);
        atomicAdd(&cg_part[row], s);
    }
    __syncthreads();
    if (tid < 32) atomicAdd(cg_s + b * C_ + cot * 32 + tid, cg_part[tid]);
}

// ---------------------------------------------------------------------------
// K6: copy inactive planes out = x
// ---------------------------------------------------------------------------
__global__ __launch_bounds__(256) void k_copy(const float* __restrict__ x,
                                              const float* __restrict__ mask_eff,
                                              float* __restrict__ out) {
    const int plane = blockIdx.x;
    if (mask_eff[plane] > 0.5f) return;
    const float4* s = (const float4*)(x + (size_t)plane * HW);
    float4* d = (float4*)(out + (size_t)plane * HW);
    const int tid = threadIdx.x;
    #pragma unroll
    for (int i = 0; i < 3; ++i) d[tid + i * 256] = s[tid + i * 256];
    if (tid < 16) d[tid + 768] = s[tid + 768];
}

// ---------------------------------------------------------------------------
// K7: main conv via bf16 MFMA implicit GEMM (unchanged from round 2)
// ---------------------------------------------------------------------------
#define LDSA 27648            // 9*64*48
#define LDSB 18528            // 386*48
__global__ __launch_bounds__(256, 2) void k_mfma_conv(
        const unsigned short* __restrict__ wA,
        const unsigned short* __restrict__ xT2,
        const int* __restrict__ actlist, const int* __restrict__ nact,
        float* __restrict__ out) {
    __shared__ __align__(16) unsigned char lds[LDSA + 2 * LDSB];
    const int b = blockIdx.y;
    const int na = nact[b];
    const int cot = blockIdx.x & 3;
    const int nt = blockIdx.x >> 2;
    if (cot * 64 >= na) return;

    const int tid = threadIdx.x;
    const int lane = tid & 63, wid = tid >> 6;
    const int ln = lane & 31, lk = lane >> 5;
    const int* al = actlist + b * C_;

    f32x16 acc[2][2];
    #pragma unroll
    for (int i = 0; i < 2; ++i)
        #pragma unroll
        for (int j = 0; j < 2; ++j)
            #pragma unroll
            for (int r = 0; r < 16; ++r) acc[i][j][r] = 0.f;

    const unsigned short* wAb = wA;
    #define LOAD_A(ksq, ar)                                                          \
        {                                                                            \
            _Pragma("unroll")                                                        \
            for (int i = 0; i < 4; ++i) {                                            \
                const int u = tid + i * 256;                                         \
                const int co_l = u & 63, rr = u >> 6;                                \
                const int cs = al[cot * 64 + co_l];                                  \
                ar[i] = *(const bf16x8*)(wAb + (size_t)cs * 2304 + (ksq) * 144 +     \
                                         (rr >> 1) * 16 + (rr & 1) * 8);             \
            }                                                                        \
            if (tid < 128) {                                                         \
                const int u = tid + 1024;                                            \
                const int co_l = u & 63, rr = u >> 6;                                \
                const int cs = al[cot * 64 + co_l];                                  \
                ar[4] = *(const bf16x8*)(wAb + (size_t)cs * 2304 + (ksq) * 144 +     \
                                         (rr >> 1) * 16 + (rr & 1) * 8);             \
            }                                                                        \
        }
    #define WRITE_A(ar)                                                              \
        {                                                                            \
            _Pragma("unroll")                                                        \
            for (int i = 0; i < 4; ++i) {                                            \
                const int u = tid + i * 256;                                         \
                const int co_l = u & 63, rr = u >> 6;                                \
                *(bf16x8*)(lds + (rr >> 1) * 3072 + co_l * 48 + (rr & 1) * 16) = ar[i]; \
            }                                                                        \
            if (tid < 128) {                                                         \
                const int u = tid + 1024;                                            \
                const int co_l = u & 63, rr = u >> 6;                                \
                *(bf16x8*)(lds + (rr >> 1) * 3072 + co_l * 48 + (rr & 1) * 16) = ar[4]; \
            }                                                                        \
        }
    #define LOAD_B(ksq, br)                                                          \
        {                                                                            \
            const unsigned short* src = xT2 +                                        \
                ((size_t)(b * 16 + (ksq)) * PSTRIDE + nt * 256) * 16;                \
            _Pragma("unroll")                                                        \
            for (int i = 0; i < 3; ++i) br[i] = *(const bf16x8*)(src + (tid + i * 256) * 8); \
            if (tid < 4) br[3] = *(const bf16x8*)(src + (tid + 768) * 8);            \
        }
    #define WRITE_B(br, buf)                                                         \
        {                                                                            \
            unsigned char* dst = lds + LDSA + (buf) * LDSB;                          \
            _Pragma("unroll")                                                        \
            for (int i = 0; i < 3; ++i) {                                            \
                const int u = tid + i * 256;                                         \
                *(bf16x8*)(dst + (u >> 1) * 48 + (u & 1) * 16) = br[i];              \
            }                                                                        \
            if (tid < 4) {                                                           \
                const int u = tid + 768;                                             \
                *(bf16x8*)(dst + (u >> 1) * 48 + (u & 1) * 16) = br[3];              \
            }                                                                        \
        }

    {
        bf16x8 ar[5]; bf16x8 br[4];
        LOAD_A(0, ar); LOAD_B(0, br);
        WRITE_A(ar); WRITE_B(br, 0);
    }
    __syncthreads();

    const unsigned char* abase = lds + ln * 48 + lk * 16;
    const unsigned char* bb0 = lds + LDSA + (wid * 64 + ln) * 48 + lk * 16;

    for (int k = 0; k < 16; ++k) {
        bf16x8 ar[5]; bf16x8 br[4];
        if (k < 15) { LOAD_B(k + 1, br); LOAD_A(k + 1, ar); }

        const unsigned char* bbase = bb0 + (k & 1) * LDSB;
        #pragma unroll
        for (int tap = 0; tap < 9; ++tap) {
            const int off = (tap / 3) * 64 + (tap % 3);
            bf16x8 a0 = *(const bf16x8*)(abase + tap * 3072);
            bf16x8 a1 = *(const bf16x8*)(abase + tap * 3072 + 32 * 48);
            bf16x8 b0 = *(const bf16x8*)(bbase + off * 48);
            bf16x8 b1 = *(const bf16x8*)(bbase + (off + 32) * 48);
            acc[0][0] = __builtin_amdgcn_mfma_f32_32x32x16_bf16(a0, b0, acc[0][0], 0, 0, 0);
            acc[0][1] = __builtin_amdgcn_mfma_f32_32x32x16_bf16(a0, b1, acc[0][1], 0, 0, 0);
            acc[1][0] = __builtin_amdgcn_mfma_f32_32x32x16_bf16(a1, b0, acc[1][0], 0, 0, 0);
            acc[1][1] = __builtin_amdgcn_mfma_f32_32x32x16_bf16(a1, b1, acc[1][1], 0, 0, 0);
        }
        __syncthreads();
        if (k < 15) { WRITE_A(ar); WRITE_B(br, (k + 1) & 1); }
        __syncthreads();
    }

    const int p_base = nt * 256 + wid * 64 + ln;
    float* ob = out + (size_t)b * C_ * HW;
    #pragma unroll
    for (int i = 0; i < 2; ++i)
        #pragma unroll
        for (int j = 0; j < 2; ++j) {
            const int p = p_base + j * 32;
            const int c = p & 63;
            if (c >= 56) continue;
            const int opix = (p >> 6) * 56 + c;
            #pragma unroll
            for (int r = 0; r < 16; ++r) {
                const int row = (r & 3) + 8 * (r >> 2) + 4 * lk;
                const int co_idx = cot * 64 + i * 32 + row;
                if (co_idx < na) {
                    const int co = al[co_idx];
                    ob[(size_t)co * HW + opix] = acc[i][j][r];
                }
            }
        }
    #undef LOAD_A
    #undef WRITE_A
    #undef LOAD_B
    #undef WRITE_B
}

// ---------------------------------------------------------------------------
// Fallback fp32 main conv
// ---------------------------------------------------------------------------
__device__ __forceinline__ void conv_acc7(float acc[7], const float win[3][9],
                                          const float* __restrict__ wt) {
    float w9[9];
    #pragma unroll
    for (int t = 0; t < 9; ++t) w9[t] = wt[t];
    #pragma unroll
    for (int p = 0; p < 7; ++p) {
        float s = acc[p];
        #pragma unroll
        for (int dr = 0; dr < 3; ++dr)
            #pragma unroll
            for (int dk = 0; dk < 3; ++dk)
                s = fmaf(win[dr][p + dk], w9[dr * 3 + dk], s);
        acc[p] = s;
    }
}

__global__ __launch_bounds__(448) void k_main_conv_fb(
        const float* __restrict__ x, const float* __restrict__ w,
        const float* __restrict__ mask_eff, float* __restrict__ out) {
    __shared__ float lds[58 * 58];
    const int b = blockIdx.y, cog = blockIdx.x, tid = threadIdx.x;
    const int co0 = cog * 4;
    const float* xb = x + (size_t)b * C_ * HW;
    float* ob = out + (size_t)b * C_ * HW;

    int m0 = (mask_eff[b * C_ + co0 + 0] > 0.5f) ? 1 : 0;
    int m1 = (mask_eff[b * C_ + co0 + 1] > 0.5f) ? 1 : 0;
    int m2 = (mask_eff[b * C_ + co0 + 2] > 0.5f) ? 1 : 0;
    int m3 = (mask_eff[b * C_ + co0 + 3] > 0.5f) ? 1 : 0;
    m0 = __builtin_amdgcn_readfirstlane(m0);
    m1 = __builtin_amdgcn_readfirstlane(m1);
    m2 = __builtin_amdgcn_readfirstlane(m2);
    m3 = __builtin_amdgcn_readfirstlane(m3);

    if (!(m0 | m1 | m2 | m3)) {
        const float4* s4 = (const float4*)(xb + (size_t)co0 * HW);
        float4* d4 = (float4*)(ob + (size_t)co0 * HW);
        for (int i = tid; i < 4 * (HW / 4); i += 448) d4[i] = s4[i];
        return;
    }
    for (int i = tid; i < 58 * 58; i += 448) lds[i] = 0.f;

    const int r = tid >> 3;
    const int c0 = (tid & 7) * 7;
    float acc0[7] = {}, acc1[7] = {}, acc2[7] = {}, acc3[7] = {};

    for (int ci = 0; ci < C_; ++ci) {
        __syncthreads();
        const float4* xp = (const float4*)(xb + (size_t)ci * HW);
        for (int i = tid; i < HW / 4; i += 448) {
            float4 v = xp[i];
            const int idx = i << 2;
            const int row = idx / 56;
            const int col = idx - row * 56;
            float* d = &lds[(row + 1) * 58 + (col + 1)];
            d[0] = v.x; d[1] = v.y; d[2] = v.z; d[3] = v.w;
        }
        __syncthreads();
        float win[3][9];
        #pragma unroll
        for (int dr = 0; dr < 3; ++dr)
            #pragma unroll
            for (int kk = 0; kk < 9; ++kk)
                win[dr][kk] = lds[(r + dr) * 58 + c0 + kk];
        const float* wrow = w + (size_t)(co0 * C_ + ci) * 9;
        if (m0) conv_acc7(acc0, win, wrow);
        if (m1) conv_acc7(acc1, win, wrow + (size_t)1 * C_ * 9);
        if (m2) conv_acc7(acc2, win, wrow + (size_t)2 * C_ * 9);
        if (m3) conv_acc7(acc3, win, wrow + (size_t)3 * C_ * 9);
    }
    const int obase = r * 56 + c0;
    auto write_co = [&](int j, int act, const float acc[7]) {
        if (act) {
            float* op = ob + (size_t)(co0 + j) * HW;
            #pragma unroll
            for (int p = 0; p < 7; ++p) op[obase + p] = acc[p];
        } else {
            const float4* s4 = (const float4*)(xb + (size_t)(co0 + j) * HW);
            float4* d4 = (float4*)(ob + (size_t)(co0 + j) * HW);
            for (int i = tid; i < HW / 4; i += 448) d4[i] = s4[i];
        }
    };
    write_co(0, m0, acc0);
    write_co(1, m1, acc1);
    write_co(2, m2, acc2);
    write_co(3, m3, acc3);
}

// ---------------------------------------------------------------------------
extern "C" void kernel_launch(void* const* d_in, const int* in_sizes, int n_in,
                              void* d_out, int out_size, void* d_ws, size_t ws_size,
                              hipStream_t stream) {
    const float* x      = (const float*)d_in[0];
    const float* conv_w = (const float*)d_in[1];
    const float* cg_w   = (const float*)d_in[2];
    const float* cg_b   = (const float*)d_in[3];
    const float* cg_fcw = (const float*)d_in[4];
    const float* cg_fcb = (const float*)d_in[5];
    const float* lg_w   = (const float*)d_in[6];
    const float* lg_b   = (const float*)d_in[7];
    const float* w_ih   = (const float*)d_in[8];
    // d_in[9] = lstm_w_hh: unused (h_prev = 0 in reference)
    const float* b_ih   = (const float*)d_in[10];
    const float* b_hh   = (const float*)d_in[11];
    const float* lg_fcw = (const float*)d_in[12];
    const float* lg_fcb = (const float*)d_in[13];
    float* out = (float*)d_out;

    char* ws = (char*)d_ws;
    float* g_mean   = (float*)(ws + 0);          // 32768
    float* cg_s     = (float*)(ws + 32768);      // 32768
    float* mask_eff = (float*)(ws + 65536);      // 32768
    float* layer    = (float*)(ws + 98304);      // 128
    int*   nact     = (int*)  (ws + 98432);      // 128
    int*   actlist  = (int*)  (ws + 98560);      // 32768
    unsigned short* wA    = (unsigned short*)(ws + 131584);     // 1,179,648
    unsigned short* wg_hi = (unsigned short*)(ws + 1311232);    // 1,179,648
    unsigned short* wg_lo = (unsigned short*)(ws + 2490880);    // 1,179,648
    unsigned short* xT2   = (unsigned short*)(ws + 3670528);    // 61,865,984
    unsigned short* xT2lo = (unsigned short*)(ws + 65536512);   // 61,865,984
    const size_t WS_FULL = 127402496ull;
    const size_t WS_MID  = 65536512ull;

    k_mean<<<B_ * C_, 256, 0, stream>>>(x, g_mean);
    k_layer_gate<<<B_, 64, 0, stream>>>(g_mean, lg_w, lg_b, w_ih, b_ih, b_hh,
                                        lg_fcw, lg_fcb, layer);

    if (ws_size >= WS_FULL) {
        // full path: MFMA main conv + split-bf16 MFMA gate conv
        k_pack_w<<<C_, 256, 0, stream>>>(conv_w, wA);
        k_pack_wg<<<C_, 256, 0, stream>>>(cg_w, wg_hi, wg_lo);
        k_pack_x<<<B_ * 16, 256, 0, stream>>>(x, xT2, xT2lo, 1);
        hipMemsetAsync(cg_s, 0, B_ * C_ * sizeof(float), stream);
        k_cg_mfma<<<dim3(24, B_), 256, 0, stream>>>(wg_hi, wg_lo, xT2, xT2lo,
                                                    cg_b, cg_s);
        k_channel_fc<<<B_, 256, 0, stream>>>(cg_s, cg_fcw, cg_fcb, layer,
                                             mask_eff, nact, actlist, 1.f / 729.f);
        k_copy<<<B_ * C_, 256, 0, stream>>>(x, mask_eff, out);
        k_mfma_conv<<<dim3(4 * NT_, B_), 256, 0, stream>>>(wA, xT2, actlist, nact, out);
    } else if (ws_size >= WS_MID) {
        // mid path: MFMA main conv + fp32 gate conv (round-2 behavior)
        k_cg_conv<<<dim3(32, 32), 256, 0, stream>>>(x, cg_w, cg_b, cg_s);
        k_channel_fc<<<B_, 256, 0, stream>>>(cg_s, cg_fcw, cg_fcb, layer,
                                             mask_eff, nact, actlist, 1.f);
        k_pack_w<<<C_, 256, 0, stream>>>(conv_w, wA);
        k_pack_x<<<B_ * 16, 256, 0, stream>>>(x, xT2, xT2, 0);
        k_copy<<<B_ * C_, 256, 0, stream>>>(x, mask_eff, out);
        k_mfma_conv<<<dim3(4 * NT_, B_), 256, 0, stream>>>(wA, xT2, actlist, nact, out);
    } else {
        // low path: all fp32
        k_cg_conv<<<dim3(32, 32), 256, 0, stream>>>(x, cg_w, cg_b, cg_s);
        k_channel_fc<<<B_, 256, 0, stream>>>(cg_s, cg_fcw, cg_fcb, layer,
                                             mask_eff, nact, actlist, 1.f);
        k_main_conv_fb<<<dim3(64, 32), 448, 0, stream>>>(x, conv_w, mask_eff, out);
    }
}